// Round 14
// baseline (474.579 us; speedup 1.0000x reference)
//
#include <hip/hip_runtime.h>
#include <stdint.h>

// ---------------- problem constants ----------------
#define S_LEN 2048
#define HID   2048
#define NHEAD 16
#define HD    128     // head dim
#define NQK   8192    // concat q,k rows of [w_q; w_k]
#define K_HID 2048

typedef _Float16 f16x8 __attribute__((ext_vector_type(8)));
typedef float    f32x4 __attribute__((ext_vector_type(4)));

__device__ __forceinline__ unsigned short f2h(float f) {
    _Float16 h = (_Float16)f;                    // RNE
    union { _Float16 h; unsigned short u; } c; c.h = h;
    return c.u;
}
__device__ __forceinline__ float h2f(unsigned short b) {
    union { unsigned short u; _Float16 h; } c; c.u = b;
    return (float)c.h;
}
__device__ __forceinline__ float softplus_f(float x) {
    return (x > 20.f) ? x : log1pf(expf(x));
}
// 2 f32 -> packed 2xfp16 (RTZ) in one v_cvt_pkrtz
__device__ __forceinline__ unsigned pk2h(float a, float b) {
    auto w = __builtin_amdgcn_cvt_pkrtz(a, b);
    union { decltype(w) h; unsigned u; } c; c.h = w;
    return c.u;
}
#define EXP2F(x) __builtin_amdgcn_exp2f(x)
#define LOG2E 1.44269504088896f
// async global->LDS, 16 B/lane; LDS dest = wave-uniform base + lane*16
__device__ __forceinline__ void gload_lds16(const unsigned short* g, unsigned short* l) {
    __builtin_amdgcn_global_load_lds(
        (const __attribute__((address_space(1))) unsigned int*)g,
        (__attribute__((address_space(3))) unsigned int*)l, 16, 0, 0);
}
// raw barrier (no vmcnt drain) + compiler memory fences
__device__ __forceinline__ void bar() {
    asm volatile("" ::: "memory");
    __builtin_amdgcn_s_barrier();
    asm volatile("" ::: "memory");
}
#define VMCNT(n) asm volatile("s_waitcnt vmcnt(" #n ")" ::: "memory")

// ---------------- fused cast fp32 -> fp16, 5 segments ----------------
__global__ __launch_bounds__(256) void cast5(const float* __restrict__ hs,
                                             const float* __restrict__ wq,
                                             const float* __restrict__ wk,
                                             const float* __restrict__ wv,
                                             const float* __restrict__ wo,
                                             unsigned short* __restrict__ hs16,
                                             unsigned short* __restrict__ wqk16,
                                             unsigned short* __restrict__ wv16,
                                             unsigned short* __restrict__ wo16) {
    int b = blockIdx.x;
    const float* src;
    unsigned short* dst;
    int i;
    if (b < 4096)       { src = hs; dst = hs16;                          i = b; }
    else if (b < 12288) { src = wq; dst = wqk16;                         i = b - 4096; }
    else if (b < 20480) { src = wk; dst = wqk16 + (size_t)4096 * K_HID;  i = b - 12288; }
    else if (b < 24576) { src = wv; dst = wv16;                          i = b - 20480; }
    else                { src = wo; dst = wo16;                          i = b - 24576; }
    int idx = i * 256 + threadIdx.x;
    float4 v = ((const float4*)src)[idx];
    ushort4 o;
    o.x = f2h(v.x); o.y = f2h(v.y); o.z = f2h(v.z); o.w = f2h(v.w);
    ((ushort4*)dst)[idx] = o;
}

// ---------------- shared NT-GEMM body (fp16 in, fp16 or fp32 out) ----------
// 128x128 tile, BK=32, 4 waves (2x2), 4x4 MFMA tiles/wave; m97 staging.
// C/D layout: col = lane&15, row = (lane>>4)*4 + reg  (harness-verified)
template <bool OUT_F16>
__device__ __forceinline__ void gemm_body(const unsigned short* __restrict__ A,
                                          const unsigned short* __restrict__ B,
                                          void* __restrict__ Cv,
                                          int m0, int n0, int N,
                                          unsigned short* As, unsigned short* Bs) {
    const int t    = threadIdx.x;
    const int wave = t >> 6;
    const int lane = t & 63;
    const int wm   = wave >> 1, wn = wave & 1;
    const int lrow = lane & 15, quad = lane >> 4;
    const int srow = lane >> 2;
    const int scol = (lane & 3) * 8;

    f32x4 acc[4][4];
    for (int i = 0; i < 4; ++i)
        for (int j = 0; j < 4; ++j)
            acc[i][j] = (f32x4){0.f, 0.f, 0.f, 0.f};

    for (int k0 = 0; k0 < K_HID; k0 += 32) {
        for (int c = 0; c < 2; ++c) {
            int ch = wave * 2 + c;     // 0..7
            int row = ch * 16 + srow;  // 0..127
            gload_lds16(A + (size_t)(m0 + row) * K_HID + k0 + scol, &As[ch * 512]);
            gload_lds16(B + (size_t)(n0 + row) * K_HID + k0 + scol, &Bs[ch * 512]);
        }
        __syncthreads();

        f16x8 af[4], bfr[4];
        for (int tm = 0; tm < 4; ++tm)
            af[tm]  = *(const f16x8*)(&As[(wm * 64 + tm * 16 + lrow) * 32 + quad * 8]);
        for (int tn = 0; tn < 4; ++tn)
            bfr[tn] = *(const f16x8*)(&Bs[(wn * 64 + tn * 16 + lrow) * 32 + quad * 8]);
        for (int tm = 0; tm < 4; ++tm)
            for (int tn = 0; tn < 4; ++tn)
                acc[tm][tn] = __builtin_amdgcn_mfma_f32_16x16x32_f16(af[tm], bfr[tn], acc[tm][tn], 0, 0, 0);
        __syncthreads();
    }

    for (int tm = 0; tm < 4; ++tm)
        for (int tn = 0; tn < 4; ++tn) {
            int col = n0 + wn * 64 + tn * 16 + lrow;
            for (int r = 0; r < 4; ++r) {
                int row = m0 + wm * 64 + tm * 16 + quad * 4 + r;
                if (OUT_F16)
                    ((unsigned short*)Cv)[(size_t)row * N + col] = f2h(acc[tm][tn][r]);
                else
                    ((float*)Cv)[(size_t)row * N + col] = acc[tm][tn][r];
            }
        }
}

// ---------------- prep body (shared by standalone + fused kernels) ---------
// Q side and kbias PRE-SCALED by log2(e) so attention can use exp2 (native).
__device__ __forceinline__ void prep_body(int gid, int lane,
                                          const unsigned short* __restrict__ qk,
                                          const float* __restrict__ cosb,
                                          const float* __restrict__ sinb,
                                          unsigned short* __restrict__ Q16,
                                          unsigned short* __restrict__ K16,
                                          float* __restrict__ kbias) {
    int h = gid >> 11;
    int s = gid & 2047;
    int d1 = lane, d2 = lane + 64;
    const unsigned short* row = qk + (size_t)s * NQK;
    float c1 = cosb[s * HD + d1], c2 = cosb[s * HD + d2];
    float s1 = sinb[s * HD + d1], s2 = sinb[s * HD + d2];
    size_t ob = ((size_t)h * S_LEN + s) * HD;

    {   // Q side (scaled by log2e)
        int base = h * 256;
        float mu1 = h2f(row[base + d1]),       mu2 = h2f(row[base + d2]);
        float sg1 = softplus_f(h2f(row[base + 128 + d1])) + 1e-4f;
        float sg2 = softplus_f(h2f(row[base + 128 + d2])) + 1e-4f;
        float w1 = mu1 * rsqrtf(sg1), w2 = mu2 * rsqrtf(sg2);
        float o1 = w1 * c1 - w2 * s1;
        float o2 = w2 * c2 + w1 * s2;
        Q16[ob + d1] = f2h(o1 * LOG2E);
        Q16[ob + d2] = f2h(o2 * LOG2E);
    }
    {   // K side (unscaled) + bias from ROUNDED k̂, scaled by log2e
        int base = 4096 + h * 256;
        float mu1 = h2f(row[base + d1]),       mu2 = h2f(row[base + d2]);
        float sg1 = softplus_f(h2f(row[base + 128 + d1])) + 1e-4f;
        float sg2 = softplus_f(h2f(row[base + 128 + d2])) + 1e-4f;
        float w1 = mu1 * rsqrtf(sg1), w2 = mu2 * rsqrtf(sg2);
        float o1 = w1 * c1 - w2 * s1;
        float o2 = w2 * c2 + w1 * s2;
        unsigned short k1 = f2h(o1), k2 = f2h(o2);
        K16[ob + d1] = k1; K16[ob + d2] = k2;
        float r1 = h2f(k1), r2 = h2f(k2);
        float part = r1 * r1 + r2 * r2 + logf(sg1) + logf(sg2);
        for (int off = 32; off > 0; off >>= 1) part += __shfl_down(part, off);
        if (lane == 0) kbias[(size_t)h * S_LEN + s] = -0.5f * LOG2E * part;
    }
}

// legacy fused launch (fallback only): QK projection + V^T projection
__global__ __launch_bounds__(256) void gemm_qkv(const unsigned short* __restrict__ hs16,
                                                const unsigned short* __restrict__ wqk16,
                                                const unsigned short* __restrict__ wv16,
                                                unsigned short* __restrict__ qk16,
                                                unsigned short* __restrict__ Vt) {
    __shared__ __align__(16) unsigned short As[128 * 32];
    __shared__ __align__(16) unsigned short Bs[128 * 32];
    int b = blockIdx.x;
    if (b < 1024) {
        gemm_body<true>(hs16, wqk16, qk16, (b >> 6) * 128, (b & 63) * 128, NQK, As, Bs);
    } else {
        b -= 1024;
        gemm_body<true>(wv16, hs16, Vt, (b >> 4) * 128, (b & 15) * 128, S_LEN, As, Bs);
    }
}

// plain single GEMM (128^2 tile; used for O-projection)
template <bool OUT_F16>
__global__ __launch_bounds__(256) void gemm_nt_f16(const unsigned short* __restrict__ A,
                                                   const unsigned short* __restrict__ B,
                                                   void* __restrict__ Cv,
                                                   int M, int N, int Kd) {
    __shared__ __align__(16) unsigned short As[128 * 32];
    __shared__ __align__(16) unsigned short Bs[128 * 32];
    gemm_body<OUT_F16>(A, B, Cv, blockIdx.y * 128, blockIdx.x * 128, N, As, Bs);
}

// ---------------- FUSED launch: V^T projection + prep + counter reset ------
// Blocks 0..255: Vt 128^2 tiles; blocks 256..8447: prep rows. Block 256 also
// zeroes the 256 split-k pair counters (region is stale w_qk16, dead after
// gemm256; stream order guarantees zeros before flash; graph replay re-zeroes).
__global__ __launch_bounds__(256) void vt_prep(const unsigned short* __restrict__ wv16,
                                               const unsigned short* __restrict__ hs16,
                                               unsigned short* __restrict__ Vt,
                                               const unsigned short* __restrict__ qk16,
                                               const float* __restrict__ cosb,
                                               const float* __restrict__ sinb,
                                               unsigned short* __restrict__ Q16,
                                               unsigned short* __restrict__ K16,
                                               float* __restrict__ kbias,
                                               unsigned int* __restrict__ cnt) {
    __shared__ __align__(16) unsigned short As[128 * 32];
    __shared__ __align__(16) unsigned short Bs[128 * 32];
    int b = blockIdx.x;
    if (b < 256) {
        gemm_body<true>(wv16, hs16, Vt, (b >> 4) * 128, (b & 15) * 128, S_LEN, As, Bs);
    } else {
        if (b == 256 && cnt) cnt[threadIdx.x] = 0;   // 256 counters, 1/thread
        int gid = (b - 256) * 4 + (threadIdx.x >> 6);
        prep_body(gid, threadIdx.x & 63, qk16, cosb, sinb, Q16, K16, kbias);
    }
}

// standalone prep (fallback path only)
__global__ __launch_bounds__(256) void prep_qk(const unsigned short* __restrict__ qk,
                                               const float* __restrict__ cosb,
                                               const float* __restrict__ sinb,
                                               unsigned short* __restrict__ Q16,
                                               unsigned short* __restrict__ K16,
                                               float* __restrict__ kbias) {
    int gid = blockIdx.x * 4 + (threadIdx.x >> 6);
    prep_body(gid, threadIdx.x & 63, qk, cosb, sinb, Q16, K16, kbias);
}

// ---------------- 256x256 cross-phase GEMM for QK projection ---------------
// CHAMPION (R2/R3): zigzag quadrant walk, counted vmcnt, 4 barriers/tile.
__global__ __launch_bounds__(512, 2) void gemm256_qk(const unsigned short* __restrict__ A,
                                                     const unsigned short* __restrict__ B,
                                                     unsigned short* __restrict__ C) {
    extern __shared__ __align__(16) unsigned short lds[];   // 65536 halves
    const int t    = threadIdx.x;
    const int wave = t >> 6;
    const int lane = t & 63;
    const int wm   = wave >> 2, wn = wave & 3;     // 2 x 4 wave grid
    const int lrow = lane & 15, quad = lane >> 4;

    const int x  = blockIdx.x & 7;
    const int sl = blockIdx.x >> 3;                // 0..31
    const int tm = ((x >> 2) << 2) + (sl >> 3);    // 0..7
    const int tn = ((x & 3) << 3) + (sl & 7);      // 0..31
    const int m0 = tm << 8, n0 = tn << 8;

    const int srow = lane >> 2;                               // row in subtile
    const int scol = ((lane & 3) * 8) ^ ((lane >> 5) << 4);   // halves
    const unsigned short* Ag = A + (size_t)(m0 + wave * 16 + srow) * K_HID + scol;
    const unsigned short* Bg = B + (size_t)(n0 + wave * 16 + srow) * K_HID + scol;

    const int swz = (lrow * 32 + quad * 8) ^ ((lrow >> 3) << 4);

    f32x4 acc[8][4];
    #pragma unroll
    for (int i = 0; i < 8; ++i)
        #pragma unroll
        for (int j = 0; j < 4; ++j) acc[i][j] = (f32x4){0.f, 0.f, 0.f, 0.f};

    {
        unsigned short* la = lds + wave * 1024;
        gload_lds16(Ag,               la);
        gload_lds16(Ag + 32,          la + 512);
        gload_lds16(Ag + 262144,      la + 8192);
        gload_lds16(Ag + 262144 + 32, la + 8704);
        unsigned short* lb = la + 16384;
        gload_lds16(Bg,               lb);
        gload_lds16(Bg + 32,          lb + 512);
        gload_lds16(Bg + 262144,      lb + 8192);
        gload_lds16(Bg + 262144 + 32, lb + 8704);
    }
    VMCNT(0);
    bar();   // tile 0 published

    // persistent across iterations (consumed by deferred Q(1,0))
    f16x8 ah[4][2], b01[2][2];

    const int NT = K_HID / 64;   // 32
    #pragma unroll 1
    for (int t2 = 0; t2 < NT; ++t2) {
        const int buf = t2 & 1;
        const unsigned short* Lb = lds + buf * 32768;
        unsigned short*       Ln = lds + (buf ^ 1) * 32768 + wave * 1024;
        const int k1  = (t2 + 1) * 64;
        const bool pre = (t2 < NT - 1);

        f16x8 al[4][2], b23[2][2];

        // ---- S0: stage A(t+1) | read al(t) | MFMA Q(1,0) of t-1 | read b01(t) ----
        if (pre) {
            gload_lds16(Ag + k1,               Ln);
            gload_lds16(Ag + k1 + 32,          Ln + 512);
            gload_lds16(Ag + 262144 + k1,      Ln + 8192);
            gload_lds16(Ag + 262144 + k1 + 32, Ln + 8704);
        }
        #pragma unroll
        for (int i = 0; i < 4; ++i) {
            al[i][0] = *(const f16x8*)(Lb + (wm * 8 + i) * 1024 + swz);
            al[i][1] = *(const f16x8*)(Lb + (wm * 8 + i) * 1024 + 512 + swz);
        }
        if (t2) {   // deferred quadrant of previous tile: pure-register
            __builtin_amdgcn_s_setprio(1);
            #pragma unroll
            for (int i = 0; i < 4; ++i)
                #pragma unroll
                for (int j = 0; j < 2; ++j) {
                    acc[4 + i][j] = __builtin_amdgcn_mfma_f32_16x16x32_f16(ah[i][0], b01[j][0], acc[4 + i][j], 0, 0, 0);
                    acc[4 + i][j] = __builtin_amdgcn_mfma_f32_16x16x32_f16(ah[i][1], b01[j][1], acc[4 + i][j], 0, 0, 0);
                }
            __builtin_amdgcn_s_setprio(0);
        }
        #pragma unroll
        for (int j = 0; j < 2; ++j) {   // overwrites b01 AFTER its last use above
            b01[j][0] = *(const f16x8*)(Lb + 16384 + (wn * 4 + j) * 1024 + swz);
            b01[j][1] = *(const f16x8*)(Lb + 16384 + (wn * 4 + j) * 1024 + 512 + swz);
        }
        bar();

        // ---- S1: stage B(t+1) | read b23(t) || MFMA Q(0,0) = al*b01 ----
        if (pre) {
            gload_lds16(Bg + k1,               Ln + 16384);
            gload_lds16(Bg + k1 + 32,          Ln + 16896);
            gload_lds16(Bg + 262144 + k1,      Ln + 24576);
            gload_lds16(Bg + 262144 + k1 + 32, Ln + 25088);
        }
        #pragma unroll
        for (int j = 0; j < 2; ++j) {
            b23[j][0] = *(const f16x8*)(Lb + 16384 + (wn * 4 + 2 + j) * 1024 + swz);
            b23[j][1] = *(const f16x8*)(Lb + 16384 + (wn * 4 + 2 + j) * 1024 + 512 + swz);
        }
        __builtin_amdgcn_s_setprio(1);
        #pragma unroll
        for (int i = 0; i < 4; ++i)
            #pragma unroll
            for (int j = 0; j < 2; ++j) {
                acc[i][j] = __builtin_amdgcn_mfma_f32_16x16x32_f16(al[i][0], b01[j][0], acc[i][j], 0, 0, 0);
                acc[i][j] = __builtin_amdgcn_mfma_f32_16x16x32_f16(al[i][1], b01[j][1], acc[i][j], 0, 0, 0);
            }
        __builtin_amdgcn_s_setprio(0);
        bar();

        // ---- S2: read ah(t) || MFMA Q(0,1) = al*b23 ----
        #pragma unroll
        for (int i = 0; i < 4; ++i) {
            ah[i][0] = *(const f16x8*)(Lb + (wm * 8 + 4 + i) * 1024 + swz);
            ah[i][1] = *(const f16x8*)(Lb + (wm * 8 + 4 + i) * 1024 + 512 + swz);
        }
        __builtin_amdgcn_s_setprio(1);
        #pragma unroll
        for (int i = 0; i < 4; ++i)
            #pragma unroll
            for (int j = 0; j < 2; ++j) {
                acc[i][2 + j] = __builtin_amdgcn_mfma_f32_16x16x32_f16(al[i][0], b23[j][0], acc[i][2 + j], 0, 0, 0);
                acc[i][2 + j] = __builtin_amdgcn_mfma_f32_16x16x32_f16(al[i][1], b23[j][1], acc[i][2 + j], 0, 0, 0);
            }
        __builtin_amdgcn_s_setprio(0);
        bar();

        // ---- S3: MFMA Q(1,1) = ah*b23 ; publish tile t+1 ----
        __builtin_amdgcn_s_setprio(1);
        #pragma unroll
        for (int i = 0; i < 4; ++i)
            #pragma unroll
            for (int j = 0; j < 2; ++j) {
                acc[4 + i][2 + j] = __builtin_amdgcn_mfma_f32_16x16x32_f16(ah[i][0], b23[j][0], acc[4 + i][2 + j], 0, 0, 0);
                acc[4 + i][2 + j] = __builtin_amdgcn_mfma_f32_16x16x32_f16(ah[i][1], b23[j][1], acc[4 + i][2 + j], 0, 0, 0);
            }
        __builtin_amdgcn_s_setprio(0);
        VMCNT(0);   // queue holds only tile t+1's 8 loads (issued in S0/S1)
        bar();      // tile t+1 published; Q(1,0) of tile t deferred to next S0
    }

    // deferred final quadrant Q(1,0) of the last tile
    __builtin_amdgcn_s_setprio(1);
    #pragma unroll
    for (int i = 0; i < 4; ++i)
        #pragma unroll
        for (int j = 0; j < 2; ++j) {
            acc[4 + i][j] = __builtin_amdgcn_mfma_f32_16x16x32_f16(ah[i][0], b01[j][0], acc[4 + i][j], 0, 0, 0);
            acc[4 + i][j] = __builtin_amdgcn_mfma_f32_16x16x32_f16(ah[i][1], b01[j][1], acc[4 + i][j], 0, 0, 0);
        }
    __builtin_amdgcn_s_setprio(0);

    #pragma unroll
    for (int m = 0; m < 8; ++m)
        #pragma unroll
        for (int n = 0; n < 4; ++n) {
            const int col = n0 + wn * 64 + n * 16 + lrow;
            #pragma unroll
            for (int r = 0; r < 4; ++r) {
                const int row = m0 + wm * 128 + m * 16 + quad * 4 + r;
                C[(size_t)row * NQK + col] = f2h(acc[m][n][r]);
            }
        }
}

// ---------------- flash attention + split-k atomic merge tail --------------
// CHAMPION (R3/R4/R11) + R14: after the epilogue, each block fences + bumps a
// per-(h,qtile) counter; the SECOND arriver merges both key-halves (math and
// f2h rounding identical to flash_merge -> bit-identical Obf). Saves the
// flash_merge launch (~8 us kernel + ~22 us gap). Staging untouched.
__global__ __launch_bounds__(256, 2) void flash_mfma(const unsigned short* __restrict__ Q16,
                                                     const unsigned short* __restrict__ K16,
                                                     const unsigned short* __restrict__ Vt,
                                                     const float* __restrict__ kbias,
                                                     unsigned short* __restrict__ OP,
                                                     float* __restrict__ ML,
                                                     unsigned int* __restrict__ cnt,
                                                     unsigned short* __restrict__ Obf) {
    constexpr int LV = 72;   // P row pad
    __shared__ __align__(16) unsigned short Khs[4 * 64 * 32];    // 16 KB
    __shared__ __align__(16) unsigned short Vts[2 * 128 * 32];   // 16 KB
    __shared__ __align__(16) unsigned short Ps[128 * LV];        // 18.4 KB
    __shared__ float kb[64];
    __shared__ unsigned oldv;

    const int t    = threadIdx.x;
    const int bb   = blockIdx.x;
    const int cc   = (bb & 7) | (((bb >> 7) & 3) << 3);   // combo 0..31
    const int h    = cc & 15;
    const int kz   = cc >> 4;
    const int q0   = ((bb >> 3) & 15) * 128;
    const int wave = t >> 6;
    const int lane = t & 63;
    const int lrow = lane & 15, quad = lane >> 4;
    const int srow = lane >> 2;
    const int scol = (lane & 3) * 8;

    f16x8 qf[2][4];
    for (int m = 0; m < 2; ++m) {
        size_t rb = ((size_t)h * S_LEN + q0 + wave * 32 + m * 16 + lrow) * HD;
        for (int kk = 0; kk < 4; ++kk)
            qf[m][kk] = *(const f16x8*)(Q16 + rb + kk * 32 + quad * 8);
    }

    float mrow[2], lsum[2];   // per-lane: q-row m*16+lrow (lsum = quad-partial)
    f32x4 Ofr[2][8];
    for (int m = 0; m < 2; ++m) { mrow[m] = -INFINITY; lsum[m] = 0.f; }
    for (int m = 0; m < 2; ++m)
        for (int d = 0; d < 8; ++d) Ofr[m][d] = (f32x4){0.f, 0.f, 0.f, 0.f};

    const int kbeg = kz * 1024;
    for (int k0 = kbeg; k0 < kbeg + 1024; k0 += 64) {
        {
            const unsigned short* kgb = K16 + ((size_t)h * S_LEN + k0) * HD;
            const unsigned short* vgb = Vt + ((size_t)h * HD) * S_LEN + k0;
            for (int c = 0; c < 4; ++c) {
                int ch = wave * 4 + c;                 // 0..15
                int kk = ch >> 2;
                int r  = (ch & 3) * 16 + srow;
                gload_lds16(kgb + (size_t)r * HD + kk * 32 + scol, &Khs[ch * 512]);
                int kc = ch >> 3;
                int r2 = (ch & 7) * 16 + srow;
                gload_lds16(vgb + (size_t)r2 * S_LEN + kc * 32 + scol, &Vts[ch * 512]);
            }
            if (t < 64) kb[t] = kbias[(size_t)h * S_LEN + k0 + t];
        }
        __syncthreads();

        // kb fragment (per C-row = k); used as MFMA C-init
        f32x4 kbv[4];
        #pragma unroll
        for (int nt = 0; nt < 4; ++nt)
            kbv[nt] = *(const f32x4*)(&kb[nt * 16 + quad * 4]);

        // QK^T swapped with bias as C-init: sc = kb + K.Q
        f32x4 sc[2][4];
        #pragma unroll
        for (int m = 0; m < 2; ++m)
            #pragma unroll
            for (int nt = 0; nt < 4; ++nt) sc[m][nt] = kbv[nt];
        for (int kk = 0; kk < 4; ++kk)
            for (int nt = 0; nt < 4; ++nt) {
                f16x8 khf = *(const f16x8*)(&Khs[kk * 2048 + (nt * 16 + lrow) * 32 + quad * 8]);
                sc[0][nt] = __builtin_amdgcn_mfma_f32_16x16x32_f16(khf, qf[0][kk], sc[0][nt], 0, 0, 0);
                sc[1][nt] = __builtin_amdgcn_mfma_f32_16x16x32_f16(khf, qf[1][kk], sc[1][nt], 0, 0, 0);
            }

        #pragma unroll
        for (int m = 0; m < 2; ++m) {
            float mx = -INFINITY;
            #pragma unroll
            for (int nt = 0; nt < 4; ++nt)
                #pragma unroll
                for (int r = 0; r < 4; ++r)
                    mx = fmaxf(mx, sc[m][nt][r]);
            mx = fmaxf(mx, __shfl_xor(mx, 16));
            mx = fmaxf(mx, __shfl_xor(mx, 32));
            // wave-uniform skip: if no q-row's max grew, alpha == 1 exactly
            if (!__all(mx <= mrow[m])) {
                float mnew  = fmaxf(mrow[m], mx);
                float alpha = EXP2F(mrow[m] - mnew);
                mrow[m] = mnew;
                lsum[m] *= alpha;
                float av0 = __shfl(alpha, quad * 4 + 0);
                float av1 = __shfl(alpha, quad * 4 + 1);
                float av2 = __shfl(alpha, quad * 4 + 2);
                float av3 = __shfl(alpha, quad * 4 + 3);
                #pragma unroll
                for (int dt = 0; dt < 8; ++dt) {
                    Ofr[m][dt][0] *= av0;
                    Ofr[m][dt][1] *= av1;
                    Ofr[m][dt][2] *= av2;
                    Ofr[m][dt][3] *= av3;
                }
            }
            float psum = 0.f;
            unsigned pw[8];
            #pragma unroll
            for (int nt = 0; nt < 4; ++nt) {
                float p0 = EXP2F(sc[m][nt][0] - mrow[m]);
                float p1 = EXP2F(sc[m][nt][1] - mrow[m]);
                float p2 = EXP2F(sc[m][nt][2] - mrow[m]);
                float p3 = EXP2F(sc[m][nt][3] - mrow[m]);
                psum += (p0 + p1) + (p2 + p3);
                pw[nt * 2]     = pk2h(p0, p1);
                pw[nt * 2 + 1] = pk2h(p2, p3);
            }
            lsum[m] += psum;
            int prow = (wave * 32 + m * 16 + lrow) * LV;
            #pragma unroll
            for (int nt = 0; nt < 4; ++nt) {
                uint2 wv; wv.x = pw[nt * 2]; wv.y = pw[nt * 2 + 1];
                *(uint2*)(&Ps[prow + nt * 16 + quad * 4]) = wv;
            }
        }

        // PV (Ps same-wave write->read; DS ops wave-ordered)
        for (int c = 0; c < 2; ++c) {
            f16x8 pa0 = *(const f16x8*)(&Ps[(wave * 32 + lrow) * LV + c * 32 + quad * 8]);
            f16x8 pa1 = *(const f16x8*)(&Ps[(wave * 32 + 16 + lrow) * LV + c * 32 + quad * 8]);
            for (int dt = 0; dt < 8; ++dt) {
                f16x8 vb = *(const f16x8*)(&Vts[c * 4096 + (dt * 16 + lrow) * 32 + quad * 8]);
                Ofr[0][dt] = __builtin_amdgcn_mfma_f32_16x16x32_f16(pa0, vb, Ofr[0][dt], 0, 0, 0);
                Ofr[1][dt] = __builtin_amdgcn_mfma_f32_16x16x32_f16(pa1, vb, Ofr[1][dt], 0, 0, 0);
            }
        }
        __syncthreads();
    }

    // epilogue: O rows in C-layout (quad*4+r); ML stats per (m,lrow) at quad 0
    size_t obase = (size_t)(kz * NHEAD + h) * S_LEN;
    for (int m = 0; m < 2; ++m) {
        float rs = lsum[m];
        rs += __shfl_xor(rs, 16);
        rs += __shfl_xor(rs, 32);
        if (quad == 0) {
            int qrow = q0 + wave * 32 + m * 16 + lrow;
            ML[(obase + qrow) * 2]     = mrow[m];
            ML[(obase + qrow) * 2 + 1] = rs;
        }
        for (int r = 0; r < 4; ++r) {
            int qrow = q0 + wave * 32 + m * 16 + quad * 4 + r;
            unsigned short* op = OP + (obase + qrow) * HD;
            for (int dt = 0; dt < 8; ++dt)
                op[dt * 16 + lrow] = f2h(Ofr[m][dt][r]);
        }
    }

    // -------- split-k merge tail: second arriver merges the pair ----------
    if (cnt) {
        __threadfence();            // this thread's OP/ML writes visible
        __syncthreads();            // all threads fenced
        if (t == 0) oldv = atomicAdd(&cnt[h * 16 + (q0 >> 7)], 1u);
        __syncthreads();
        if (oldv == 1) {            // partner half complete & visible
            __threadfence();
            for (int it = t; it < 2048; it += 256) {   // 128 rows x 16 chunks
                int row = it >> 4;
                int ck  = it & 15;
                int q   = q0 + row;
                size_t i0 = (size_t)h * S_LEN + q;
                size_t i1 = (size_t)(NHEAD + h) * S_LEN + q;
                float m0 = ML[i0 * 2], l0 = ML[i0 * 2 + 1];
                float m1 = ML[i1 * 2], l1 = ML[i1 * 2 + 1];
                float mf = fmaxf(m0, m1);
                float w0 = EXP2F(m0 - mf), w1 = EXP2F(m1 - mf);
                float inv = 1.f / (l0 * w0 + l1 * w1);
                f16x8 v0 = *(const f16x8*)(OP + i0 * HD + ck * 8);
                f16x8 v1 = *(const f16x8*)(OP + i1 * HD + ck * 8);
                f16x8 o;
                #pragma unroll
                for (int j = 0; j < 8; ++j) {
                    float ov = ((float)v0[j] * w0 + (float)v1[j] * w1) * inv;
                    o[j] = (_Float16)ov;
                }
                *(f16x8*)(Obf + (size_t)q * HID + h * HD + ck * 8) = o;
            }
        }
    }
}

// ---------------- merge (FALLBACK PATH ONLY) -------------------------------
__global__ __launch_bounds__(256) void flash_merge(const unsigned short* __restrict__ OP,
                                                   const float* __restrict__ ML,
                                                   unsigned short* __restrict__ Obf) {
    int row = blockIdx.x * 2 + (threadIdx.x >> 7);   // h*2048 + q
    int d   = threadIdx.x & 127;
    int h = row >> 11, q = row & 2047;
    size_t i0 = (size_t)h * S_LEN + q;
    size_t i1 = (size_t)(NHEAD + h) * S_LEN + q;
    float m0 = ML[i0 * 2], l0 = ML[i0 * 2 + 1];
    float m1 = ML[i1 * 2], l1 = ML[i1 * 2 + 1];
    float mf = fmaxf(m0, m1);
    float w0 = EXP2F(m0 - mf), w1 = EXP2F(m1 - mf);
    float inv = 1.f / (l0 * w0 + l1 * w1);
    float o = (h2f(OP[i0 * HD + d]) * w0 + h2f(OP[i1 * HD + d]) * w1) * inv;
    Obf[(size_t)q * HID + h * HD + d] = f2h(o);
}

// ---------------- launch ----------------
extern "C" void kernel_launch(void* const* d_in, const int* in_sizes, int n_in,
                              void* d_out, int out_size, void* d_ws, size_t ws_size,
                              hipStream_t stream) {
    const float* hs   = (const float*)d_in[0];
    const float* cosb = (const float*)d_in[1];
    const float* sinb = (const float*)d_in[2];
    const float* wq   = (const float*)d_in[3];
    const float* wk   = (const float*)d_in[4];
    const float* wv   = (const float*)d_in[5];
    const float* wo   = (const float*)d_in[6];
    float* out = (float*)d_out;
    char*  ws  = (char*)d_ws;

    // ws layout (phase-lifetime aliasing, ~101 MB):
    //  [0, 33.6M):     w_qk16 (dead after QK gemm) -> Q16 | K16 | kbias | cnt@20M
    //  [33.6, 67.1M):  qk16 fp16 (dead after prep)  -> OP fp16 | ML
    //  [67.1M,...):    hs16 (->Obf) | w_v16 | w_o16 | Vt
    unsigned short* w_qk16 = (unsigned short*)(ws);
    unsigned short* Q16    = (unsigned short*)(ws);
    unsigned short* K16    = (unsigned short*)(ws + 8388608);
    float*          kbias  = (float*)(ws + 16777216);
    unsigned int*   cnt    = (unsigned int*)(ws + 20971520);      // stale w_qk16 zone
    unsigned short* qk16   = (unsigned short*)(ws + 33554432);
    unsigned short* OP     = (unsigned short*)(ws + 33554432);    // aliases qk16
    float*          ML     = (float*)(ws + 50331648);
    unsigned short* hs16   = (unsigned short*)(ws + 67108864);
    unsigned short* Obf    = (unsigned short*)(ws + 67108864);    // aliases hs16
    unsigned short* w_v16  = (unsigned short*)(ws + 75497472);
    unsigned short* w_o16  = (unsigned short*)(ws + 83886080);
    unsigned short* Vt     = (unsigned short*)(ws + 92274688);

    static int use256 = -1;
    if (use256 < 0) {
        hipError_t e = hipFuncSetAttribute((const void*)gemm256_qk,
                                           hipFuncAttributeMaxDynamicSharedMemorySize,
                                           131072);
        use256 = (e == hipSuccess) ? 1 : 0;
    }

    // fused casts (5 segments, 28672 blocks)
    cast5<<<28672, 256, 0, stream>>>(hs, wq, wk, wv, wo, hs16, w_qk16, w_v16, w_o16);

    if (use256) {
        // QK projection [2048,8192]: 256^2 cross-phase pipelined GEMM (256 blocks = 1/CU)
        gemm256_qk<<<256, 512, 131072, stream>>>(hs16, w_qk16, qk16);
        // FUSED: V^T projection (256 blocks) + prep (8192 blocks) + cnt reset
        vt_prep<<<256 + 8192, 256, 0, stream>>>(w_v16, hs16, Vt, qk16,
                                                cosb, sinb, Q16, K16, kbias, cnt);
        // flash attention with in-kernel split-k merge (no flash_merge launch)
        flash_mfma<<<512, 256, 0, stream>>>(Q16, K16, Vt, kbias, OP, ML, cnt, Obf);
        // output projection: out = Obf @ w_o^T (fp32 out)
        gemm_nt_f16<false><<<dim3(16, 16), 256, 0, stream>>>(Obf, w_o16, out, S_LEN, HID, K_HID);
    } else {
        gemm_qkv<<<1280, 256, 0, stream>>>(hs16, w_qk16, w_v16, qk16, Vt);
        prep_qk<<<(NHEAD * S_LEN) / 4, 256, 0, stream>>>(qk16, cosb, sinb,
                                                         Q16, K16, kbias);
        flash_mfma<<<512, 256, 0, stream>>>(Q16, K16, Vt, kbias, OP, ML,
                                            (unsigned int*)nullptr, (unsigned short*)nullptr);
        flash_merge<<<(NHEAD * S_LEN) / 2, 256, 0, stream>>>(OP, ML, Obf);
        gemm_nt_f16<false><<<dim3(16, 16), 256, 0, stream>>>(Obf, w_o16, out, S_LEN, HID, K_HID);
    }
}

// Round 15
// 365.981 us; speedup vs baseline: 1.2967x; 1.2967x over previous
//
#include <hip/hip_runtime.h>
#include <stdint.h>

// ---------------- problem constants ----------------
#define S_LEN 2048
#define HID   2048
#define NHEAD 16
#define HD    128     // head dim
#define NQK   8192    // concat q,k rows of [w_q; w_k]
#define K_HID 2048

typedef _Float16 f16x8 __attribute__((ext_vector_type(8)));
typedef float    f32x4 __attribute__((ext_vector_type(4)));

__device__ __forceinline__ unsigned short f2h(float f) {
    _Float16 h = (_Float16)f;                    // RNE
    union { _Float16 h; unsigned short u; } c; c.h = h;
    return c.u;
}
__device__ __forceinline__ float h2f(unsigned short b) {
    union { unsigned short u; _Float16 h; } c; c.u = b;
    return (float)c.h;
}
__device__ __forceinline__ float softplus_f(float x) {
    return (x > 20.f) ? x : log1pf(expf(x));
}
// 2 f32 -> packed 2xfp16 (RTZ) in one v_cvt_pkrtz
__device__ __forceinline__ unsigned pk2h(float a, float b) {
    auto w = __builtin_amdgcn_cvt_pkrtz(a, b);
    union { decltype(w) h; unsigned u; } c; c.h = w;
    return c.u;
}
#define EXP2F(x) __builtin_amdgcn_exp2f(x)
#define LOG2E 1.44269504088896f
// async global->LDS, 16 B/lane; LDS dest = wave-uniform base + lane*16
__device__ __forceinline__ void gload_lds16(const unsigned short* g, unsigned short* l) {
    __builtin_amdgcn_global_load_lds(
        (const __attribute__((address_space(1))) unsigned int*)g,
        (__attribute__((address_space(3))) unsigned int*)l, 16, 0, 0);
}
// raw barrier (no vmcnt drain) + compiler memory fences
__device__ __forceinline__ void bar() {
    asm volatile("" ::: "memory");
    __builtin_amdgcn_s_barrier();
    asm volatile("" ::: "memory");
}
#define VMCNT(n) asm volatile("s_waitcnt vmcnt(" #n ")" ::: "memory")

// ---------------- fused cast fp32 -> fp16, 5 segments ----------------
__global__ __launch_bounds__(256) void cast5(const float* __restrict__ hs,
                                             const float* __restrict__ wq,
                                             const float* __restrict__ wk,
                                             const float* __restrict__ wv,
                                             const float* __restrict__ wo,
                                             unsigned short* __restrict__ hs16,
                                             unsigned short* __restrict__ wqk16,
                                             unsigned short* __restrict__ wv16,
                                             unsigned short* __restrict__ wo16) {
    int b = blockIdx.x;
    const float* src;
    unsigned short* dst;
    int i;
    if (b < 4096)       { src = hs; dst = hs16;                          i = b; }
    else if (b < 12288) { src = wq; dst = wqk16;                         i = b - 4096; }
    else if (b < 20480) { src = wk; dst = wqk16 + (size_t)4096 * K_HID;  i = b - 12288; }
    else if (b < 24576) { src = wv; dst = wv16;                          i = b - 20480; }
    else                { src = wo; dst = wo16;                          i = b - 24576; }
    int idx = i * 256 + threadIdx.x;
    float4 v = ((const float4*)src)[idx];
    ushort4 o;
    o.x = f2h(v.x); o.y = f2h(v.y); o.z = f2h(v.z); o.w = f2h(v.w);
    ((ushort4*)dst)[idx] = o;
}

// ---------------- shared NT-GEMM body (fp16 in, fp16 or fp32 out) ----------
// 128x128 tile, BK=32, 4 waves (2x2), 4x4 MFMA tiles/wave; m97 staging.
// C/D layout: col = lane&15, row = (lane>>4)*4 + reg  (harness-verified)
template <bool OUT_F16>
__device__ __forceinline__ void gemm_body(const unsigned short* __restrict__ A,
                                          const unsigned short* __restrict__ B,
                                          void* __restrict__ Cv,
                                          int m0, int n0, int N,
                                          unsigned short* As, unsigned short* Bs) {
    const int t    = threadIdx.x;
    const int wave = t >> 6;
    const int lane = t & 63;
    const int wm   = wave >> 1, wn = wave & 1;
    const int lrow = lane & 15, quad = lane >> 4;
    const int srow = lane >> 2;
    const int scol = (lane & 3) * 8;

    f32x4 acc[4][4];
    for (int i = 0; i < 4; ++i)
        for (int j = 0; j < 4; ++j)
            acc[i][j] = (f32x4){0.f, 0.f, 0.f, 0.f};

    for (int k0 = 0; k0 < K_HID; k0 += 32) {
        for (int c = 0; c < 2; ++c) {
            int ch = wave * 2 + c;     // 0..7
            int row = ch * 16 + srow;  // 0..127
            gload_lds16(A + (size_t)(m0 + row) * K_HID + k0 + scol, &As[ch * 512]);
            gload_lds16(B + (size_t)(n0 + row) * K_HID + k0 + scol, &Bs[ch * 512]);
        }
        __syncthreads();

        f16x8 af[4], bfr[4];
        for (int tm = 0; tm < 4; ++tm)
            af[tm]  = *(const f16x8*)(&As[(wm * 64 + tm * 16 + lrow) * 32 + quad * 8]);
        for (int tn = 0; tn < 4; ++tn)
            bfr[tn] = *(const f16x8*)(&Bs[(wn * 64 + tn * 16 + lrow) * 32 + quad * 8]);
        for (int tm = 0; tm < 4; ++tm)
            for (int tn = 0; tn < 4; ++tn)
                acc[tm][tn] = __builtin_amdgcn_mfma_f32_16x16x32_f16(af[tm], bfr[tn], acc[tm][tn], 0, 0, 0);
        __syncthreads();
    }

    for (int tm = 0; tm < 4; ++tm)
        for (int tn = 0; tn < 4; ++tn) {
            int col = n0 + wn * 64 + tn * 16 + lrow;
            for (int r = 0; r < 4; ++r) {
                int row = m0 + wm * 64 + tm * 16 + quad * 4 + r;
                if (OUT_F16)
                    ((unsigned short*)Cv)[(size_t)row * N + col] = f2h(acc[tm][tn][r]);
                else
                    ((float*)Cv)[(size_t)row * N + col] = acc[tm][tn][r];
            }
        }
}

// ---------------- prep body (shared by standalone + fused kernels) ---------
// Q side and kbias PRE-SCALED by log2(e) so attention can use exp2 (native).
__device__ __forceinline__ void prep_body(int gid, int lane,
                                          const unsigned short* __restrict__ qk,
                                          const float* __restrict__ cosb,
                                          const float* __restrict__ sinb,
                                          unsigned short* __restrict__ Q16,
                                          unsigned short* __restrict__ K16,
                                          float* __restrict__ kbias) {
    int h = gid >> 11;
    int s = gid & 2047;
    int d1 = lane, d2 = lane + 64;
    const unsigned short* row = qk + (size_t)s * NQK;
    float c1 = cosb[s * HD + d1], c2 = cosb[s * HD + d2];
    float s1 = sinb[s * HD + d1], s2 = sinb[s * HD + d2];
    size_t ob = ((size_t)h * S_LEN + s) * HD;

    {   // Q side (scaled by log2e)
        int base = h * 256;
        float mu1 = h2f(row[base + d1]),       mu2 = h2f(row[base + d2]);
        float sg1 = softplus_f(h2f(row[base + 128 + d1])) + 1e-4f;
        float sg2 = softplus_f(h2f(row[base + 128 + d2])) + 1e-4f;
        float w1 = mu1 * rsqrtf(sg1), w2 = mu2 * rsqrtf(sg2);
        float o1 = w1 * c1 - w2 * s1;
        float o2 = w2 * c2 + w1 * s2;
        Q16[ob + d1] = f2h(o1 * LOG2E);
        Q16[ob + d2] = f2h(o2 * LOG2E);
    }
    {   // K side (unscaled) + bias from ROUNDED k̂, scaled by log2e
        int base = 4096 + h * 256;
        float mu1 = h2f(row[base + d1]),       mu2 = h2f(row[base + d2]);
        float sg1 = softplus_f(h2f(row[base + 128 + d1])) + 1e-4f;
        float sg2 = softplus_f(h2f(row[base + 128 + d2])) + 1e-4f;
        float w1 = mu1 * rsqrtf(sg1), w2 = mu2 * rsqrtf(sg2);
        float o1 = w1 * c1 - w2 * s1;
        float o2 = w2 * c2 + w1 * s2;
        unsigned short k1 = f2h(o1), k2 = f2h(o2);
        K16[ob + d1] = k1; K16[ob + d2] = k2;
        float r1 = h2f(k1), r2 = h2f(k2);
        float part = r1 * r1 + r2 * r2 + logf(sg1) + logf(sg2);
        for (int off = 32; off > 0; off >>= 1) part += __shfl_down(part, off);
        if (lane == 0) kbias[(size_t)h * S_LEN + s] = -0.5f * LOG2E * part;
    }
}

// legacy fused launch (fallback only): QK projection + V^T projection
__global__ __launch_bounds__(256) void gemm_qkv(const unsigned short* __restrict__ hs16,
                                                const unsigned short* __restrict__ wqk16,
                                                const unsigned short* __restrict__ wv16,
                                                unsigned short* __restrict__ qk16,
                                                unsigned short* __restrict__ Vt) {
    __shared__ __align__(16) unsigned short As[128 * 32];
    __shared__ __align__(16) unsigned short Bs[128 * 32];
    int b = blockIdx.x;
    if (b < 1024) {
        gemm_body<true>(hs16, wqk16, qk16, (b >> 6) * 128, (b & 63) * 128, NQK, As, Bs);
    } else {
        b -= 1024;
        gemm_body<true>(wv16, hs16, Vt, (b >> 4) * 128, (b & 15) * 128, S_LEN, As, Bs);
    }
}

// plain single GEMM (128^2 tile; used for O-projection)
template <bool OUT_F16>
__global__ __launch_bounds__(256) void gemm_nt_f16(const unsigned short* __restrict__ A,
                                                   const unsigned short* __restrict__ B,
                                                   void* __restrict__ Cv,
                                                   int M, int N, int Kd) {
    __shared__ __align__(16) unsigned short As[128 * 32];
    __shared__ __align__(16) unsigned short Bs[128 * 32];
    gemm_body<OUT_F16>(A, B, Cv, blockIdx.y * 128, blockIdx.x * 128, N, As, Bs);
}

// ---------------- FUSED launch: V^T projection + prep (independent ops) ----
// ~22 us/launch overhead measured -> merge the two independent post-gemm256
// kernels. Blocks 0..255: Vt 128^2 tiles; blocks 256..8447: prep rows.
// (Only INDEPENDENT-kernel packing wins; producer->consumer fusions that
// touch tuned kernels' staging/compilation lost 5x: R5,R6/7/8,R12,R14.)
__global__ __launch_bounds__(256) void vt_prep(const unsigned short* __restrict__ wv16,
                                               const unsigned short* __restrict__ hs16,
                                               unsigned short* __restrict__ Vt,
                                               const unsigned short* __restrict__ qk16,
                                               const float* __restrict__ cosb,
                                               const float* __restrict__ sinb,
                                               unsigned short* __restrict__ Q16,
                                               unsigned short* __restrict__ K16,
                                               float* __restrict__ kbias) {
    __shared__ __align__(16) unsigned short As[128 * 32];
    __shared__ __align__(16) unsigned short Bs[128 * 32];
    int b = blockIdx.x;
    if (b < 256) {
        gemm_body<true>(wv16, hs16, Vt, (b >> 4) * 128, (b & 15) * 128, S_LEN, As, Bs);
    } else {
        int gid = (b - 256) * 4 + (threadIdx.x >> 6);
        prep_body(gid, threadIdx.x & 63, qk16, cosb, sinb, Q16, K16, kbias);
    }
}

// standalone prep (fallback path only)
__global__ __launch_bounds__(256) void prep_qk(const unsigned short* __restrict__ qk,
                                               const float* __restrict__ cosb,
                                               const float* __restrict__ sinb,
                                               unsigned short* __restrict__ Q16,
                                               unsigned short* __restrict__ K16,
                                               float* __restrict__ kbias) {
    int gid = blockIdx.x * 4 + (threadIdx.x >> 6);
    prep_body(gid, threadIdx.x & 63, qk, cosb, sinb, Q16, K16, kbias);
}

// ---------------- 256x256 cross-phase GEMM for QK projection ---------------
// CHAMPION (R2/R3): zigzag quadrant walk, counted vmcnt, 4 barriers/tile.
__global__ __launch_bounds__(512, 2) void gemm256_qk(const unsigned short* __restrict__ A,
                                                     const unsigned short* __restrict__ B,
                                                     unsigned short* __restrict__ C) {
    extern __shared__ __align__(16) unsigned short lds[];   // 65536 halves
    const int t    = threadIdx.x;
    const int wave = t >> 6;
    const int lane = t & 63;
    const int wm   = wave >> 2, wn = wave & 3;     // 2 x 4 wave grid
    const int lrow = lane & 15, quad = lane >> 4;

    const int x  = blockIdx.x & 7;
    const int sl = blockIdx.x >> 3;                // 0..31
    const int tm = ((x >> 2) << 2) + (sl >> 3);    // 0..7
    const int tn = ((x & 3) << 3) + (sl & 7);      // 0..31
    const int m0 = tm << 8, n0 = tn << 8;

    const int srow = lane >> 2;                               // row in subtile
    const int scol = ((lane & 3) * 8) ^ ((lane >> 5) << 4);   // halves
    const unsigned short* Ag = A + (size_t)(m0 + wave * 16 + srow) * K_HID + scol;
    const unsigned short* Bg = B + (size_t)(n0 + wave * 16 + srow) * K_HID + scol;

    const int swz = (lrow * 32 + quad * 8) ^ ((lrow >> 3) << 4);

    f32x4 acc[8][4];
    #pragma unroll
    for (int i = 0; i < 8; ++i)
        #pragma unroll
        for (int j = 0; j < 4; ++j) acc[i][j] = (f32x4){0.f, 0.f, 0.f, 0.f};

    {
        unsigned short* la = lds + wave * 1024;
        gload_lds16(Ag,               la);
        gload_lds16(Ag + 32,          la + 512);
        gload_lds16(Ag + 262144,      la + 8192);
        gload_lds16(Ag + 262144 + 32, la + 8704);
        unsigned short* lb = la + 16384;
        gload_lds16(Bg,               lb);
        gload_lds16(Bg + 32,          lb + 512);
        gload_lds16(Bg + 262144,      lb + 8192);
        gload_lds16(Bg + 262144 + 32, lb + 8704);
    }
    VMCNT(0);
    bar();   // tile 0 published

    // persistent across iterations (consumed by deferred Q(1,0))
    f16x8 ah[4][2], b01[2][2];

    const int NT = K_HID / 64;   // 32
    #pragma unroll 1
    for (int t2 = 0; t2 < NT; ++t2) {
        const int buf = t2 & 1;
        const unsigned short* Lb = lds + buf * 32768;
        unsigned short*       Ln = lds + (buf ^ 1) * 32768 + wave * 1024;
        const int k1  = (t2 + 1) * 64;
        const bool pre = (t2 < NT - 1);

        f16x8 al[4][2], b23[2][2];

        // ---- S0: stage A(t+1) | read al(t) | MFMA Q(1,0) of t-1 | read b01(t) ----
        if (pre) {
            gload_lds16(Ag + k1,               Ln);
            gload_lds16(Ag + k1 + 32,          Ln + 512);
            gload_lds16(Ag + 262144 + k1,      Ln + 8192);
            gload_lds16(Ag + 262144 + k1 + 32, Ln + 8704);
        }
        #pragma unroll
        for (int i = 0; i < 4; ++i) {
            al[i][0] = *(const f16x8*)(Lb + (wm * 8 + i) * 1024 + swz);
            al[i][1] = *(const f16x8*)(Lb + (wm * 8 + i) * 1024 + 512 + swz);
        }
        if (t2) {   // deferred quadrant of previous tile: pure-register
            __builtin_amdgcn_s_setprio(1);
            #pragma unroll
            for (int i = 0; i < 4; ++i)
                #pragma unroll
                for (int j = 0; j < 2; ++j) {
                    acc[4 + i][j] = __builtin_amdgcn_mfma_f32_16x16x32_f16(ah[i][0], b01[j][0], acc[4 + i][j], 0, 0, 0);
                    acc[4 + i][j] = __builtin_amdgcn_mfma_f32_16x16x32_f16(ah[i][1], b01[j][1], acc[4 + i][j], 0, 0, 0);
                }
            __builtin_amdgcn_s_setprio(0);
        }
        #pragma unroll
        for (int j = 0; j < 2; ++j) {   // overwrites b01 AFTER its last use above
            b01[j][0] = *(const f16x8*)(Lb + 16384 + (wn * 4 + j) * 1024 + swz);
            b01[j][1] = *(const f16x8*)(Lb + 16384 + (wn * 4 + j) * 1024 + 512 + swz);
        }
        bar();

        // ---- S1: stage B(t+1) | read b23(t) || MFMA Q(0,0) = al*b01 ----
        if (pre) {
            gload_lds16(Bg + k1,               Ln + 16384);
            gload_lds16(Bg + k1 + 32,          Ln + 16896);
            gload_lds16(Bg + 262144 + k1,      Ln + 24576);
            gload_lds16(Bg + 262144 + k1 + 32, Ln + 25088);
        }
        #pragma unroll
        for (int j = 0; j < 2; ++j) {
            b23[j][0] = *(const f16x8*)(Lb + 16384 + (wn * 4 + 2 + j) * 1024 + swz);
            b23[j][1] = *(const f16x8*)(Lb + 16384 + (wn * 4 + 2 + j) * 1024 + 512 + swz);
        }
        __builtin_amdgcn_s_setprio(1);
        #pragma unroll
        for (int i = 0; i < 4; ++i)
            #pragma unroll
            for (int j = 0; j < 2; ++j) {
                acc[i][j] = __builtin_amdgcn_mfma_f32_16x16x32_f16(al[i][0], b01[j][0], acc[i][j], 0, 0, 0);
                acc[i][j] = __builtin_amdgcn_mfma_f32_16x16x32_f16(al[i][1], b01[j][1], acc[i][j], 0, 0, 0);
            }
        __builtin_amdgcn_s_setprio(0);
        bar();

        // ---- S2: read ah(t) || MFMA Q(0,1) = al*b23 ----
        #pragma unroll
        for (int i = 0; i < 4; ++i) {
            ah[i][0] = *(const f16x8*)(Lb + (wm * 8 + 4 + i) * 1024 + swz);
            ah[i][1] = *(const f16x8*)(Lb + (wm * 8 + 4 + i) * 1024 + 512 + swz);
        }
        __builtin_amdgcn_s_setprio(1);
        #pragma unroll
        for (int i = 0; i < 4; ++i)
            #pragma unroll
            for (int j = 0; j < 2; ++j) {
                acc[i][2 + j] = __builtin_amdgcn_mfma_f32_16x16x32_f16(al[i][0], b23[j][0], acc[i][2 + j], 0, 0, 0);
                acc[i][2 + j] = __builtin_amdgcn_mfma_f32_16x16x32_f16(al[i][1], b23[j][1], acc[i][2 + j], 0, 0, 0);
            }
        __builtin_amdgcn_s_setprio(0);
        bar();

        // ---- S3: MFMA Q(1,1) = ah*b23 ; publish tile t+1 ----
        __builtin_amdgcn_s_setprio(1);
        #pragma unroll
        for (int i = 0; i < 4; ++i)
            #pragma unroll
            for (int j = 0; j < 2; ++j) {
                acc[4 + i][2 + j] = __builtin_amdgcn_mfma_f32_16x16x32_f16(ah[i][0], b23[j][0], acc[4 + i][2 + j], 0, 0, 0);
                acc[4 + i][2 + j] = __builtin_amdgcn_mfma_f32_16x16x32_f16(ah[i][1], b23[j][1], acc[4 + i][2 + j], 0, 0, 0);
            }
        __builtin_amdgcn_s_setprio(0);
        VMCNT(0);   // queue holds only tile t+1's 8 loads (issued in S0/S1)
        bar();      // tile t+1 published; Q(1,0) of tile t deferred to next S0
    }

    // deferred final quadrant Q(1,0) of the last tile
    __builtin_amdgcn_s_setprio(1);
    #pragma unroll
    for (int i = 0; i < 4; ++i)
        #pragma unroll
        for (int j = 0; j < 2; ++j) {
            acc[4 + i][j] = __builtin_amdgcn_mfma_f32_16x16x32_f16(ah[i][0], b01[j][0], acc[4 + i][j], 0, 0, 0);
            acc[4 + i][j] = __builtin_amdgcn_mfma_f32_16x16x32_f16(ah[i][1], b01[j][1], acc[4 + i][j], 0, 0, 0);
        }
    __builtin_amdgcn_s_setprio(0);

    #pragma unroll
    for (int m = 0; m < 8; ++m)
        #pragma unroll
        for (int n = 0; n < 4; ++n) {
            const int col = n0 + wn * 64 + n * 16 + lrow;
            #pragma unroll
            for (int r = 0; r < 4; ++r) {
                const int row = m0 + wm * 128 + m * 16 + quad * 4 + r;
                C[(size_t)row * NQK + col] = f2h(acc[m][n][r]);
            }
        }
}

// ---------------- flash attention, fp16 MFMA, key-split partials -----------
// CHAMPION (R3/R4/R11): swapped QK^T, kbias as MFMA C-init, exact
// skip-rescale, exp2 domain, XCD-remapped flat grid, K/V staged in LDS.
__global__ __launch_bounds__(256, 2) void flash_mfma(const unsigned short* __restrict__ Q16,
                                                     const unsigned short* __restrict__ K16,
                                                     const unsigned short* __restrict__ Vt,
                                                     const float* __restrict__ kbias,
                                                     unsigned short* __restrict__ OP,
                                                     float* __restrict__ ML) {
    constexpr int LV = 72;   // P row pad
    __shared__ __align__(16) unsigned short Khs[4 * 64 * 32];    // 16 KB
    __shared__ __align__(16) unsigned short Vts[2 * 128 * 32];   // 16 KB
    __shared__ __align__(16) unsigned short Ps[128 * LV];        // 18.4 KB
    __shared__ float kb[64];

    const int t    = threadIdx.x;
    const int bb   = blockIdx.x;
    const int cc   = (bb & 7) | (((bb >> 7) & 3) << 3);   // combo 0..31
    const int h    = cc & 15;
    const int kz   = cc >> 4;
    const int q0   = ((bb >> 3) & 15) * 128;
    const int wave = t >> 6;
    const int lane = t & 63;
    const int lrow = lane & 15, quad = lane >> 4;
    const int srow = lane >> 2;
    const int scol = (lane & 3) * 8;

    f16x8 qf[2][4];
    for (int m = 0; m < 2; ++m) {
        size_t rb = ((size_t)h * S_LEN + q0 + wave * 32 + m * 16 + lrow) * HD;
        for (int kk = 0; kk < 4; ++kk)
            qf[m][kk] = *(const f16x8*)(Q16 + rb + kk * 32 + quad * 8);
    }

    float mrow[2], lsum[2];   // per-lane: q-row m*16+lrow (lsum = quad-partial)
    f32x4 Ofr[2][8];
    for (int m = 0; m < 2; ++m) { mrow[m] = -INFINITY; lsum[m] = 0.f; }
    for (int m = 0; m < 2; ++m)
        for (int d = 0; d < 8; ++d) Ofr[m][d] = (f32x4){0.f, 0.f, 0.f, 0.f};

    const int kbeg = kz * 1024;
    for (int k0 = kbeg; k0 < kbeg + 1024; k0 += 64) {
        {
            const unsigned short* kgb = K16 + ((size_t)h * S_LEN + k0) * HD;
            const unsigned short* vgb = Vt + ((size_t)h * HD) * S_LEN + k0;
            for (int c = 0; c < 4; ++c) {
                int ch = wave * 4 + c;                 // 0..15
                int kk = ch >> 2;
                int r  = (ch & 3) * 16 + srow;
                gload_lds16(kgb + (size_t)r * HD + kk * 32 + scol, &Khs[ch * 512]);
                int kc = ch >> 3;
                int r2 = (ch & 7) * 16 + srow;
                gload_lds16(vgb + (size_t)r2 * S_LEN + kc * 32 + scol, &Vts[ch * 512]);
            }
            if (t < 64) kb[t] = kbias[(size_t)h * S_LEN + k0 + t];
        }
        __syncthreads();

        // kb fragment (per C-row = k); used as MFMA C-init
        f32x4 kbv[4];
        #pragma unroll
        for (int nt = 0; nt < 4; ++nt)
            kbv[nt] = *(const f32x4*)(&kb[nt * 16 + quad * 4]);

        // QK^T swapped with bias as C-init: sc = kb + K.Q
        f32x4 sc[2][4];
        #pragma unroll
        for (int m = 0; m < 2; ++m)
            #pragma unroll
            for (int nt = 0; nt < 4; ++nt) sc[m][nt] = kbv[nt];
        for (int kk = 0; kk < 4; ++kk)
            for (int nt = 0; nt < 4; ++nt) {
                f16x8 khf = *(const f16x8*)(&Khs[kk * 2048 + (nt * 16 + lrow) * 32 + quad * 8]);
                sc[0][nt] = __builtin_amdgcn_mfma_f32_16x16x32_f16(khf, qf[0][kk], sc[0][nt], 0, 0, 0);
                sc[1][nt] = __builtin_amdgcn_mfma_f32_16x16x32_f16(khf, qf[1][kk], sc[1][nt], 0, 0, 0);
            }

        #pragma unroll
        for (int m = 0; m < 2; ++m) {
            float mx = -INFINITY;
            #pragma unroll
            for (int nt = 0; nt < 4; ++nt)
                #pragma unroll
                for (int r = 0; r < 4; ++r)
                    mx = fmaxf(mx, sc[m][nt][r]);
            mx = fmaxf(mx, __shfl_xor(mx, 16));
            mx = fmaxf(mx, __shfl_xor(mx, 32));
            // wave-uniform skip: if no q-row's max grew, alpha == 1 exactly
            if (!__all(mx <= mrow[m])) {
                float mnew  = fmaxf(mrow[m], mx);
                float alpha = EXP2F(mrow[m] - mnew);
                mrow[m] = mnew;
                lsum[m] *= alpha;
                float av0 = __shfl(alpha, quad * 4 + 0);
                float av1 = __shfl(alpha, quad * 4 + 1);
                float av2 = __shfl(alpha, quad * 4 + 2);
                float av3 = __shfl(alpha, quad * 4 + 3);
                #pragma unroll
                for (int dt = 0; dt < 8; ++dt) {
                    Ofr[m][dt][0] *= av0;
                    Ofr[m][dt][1] *= av1;
                    Ofr[m][dt][2] *= av2;
                    Ofr[m][dt][3] *= av3;
                }
            }
            float psum = 0.f;
            unsigned pw[8];
            #pragma unroll
            for (int nt = 0; nt < 4; ++nt) {
                float p0 = EXP2F(sc[m][nt][0] - mrow[m]);
                float p1 = EXP2F(sc[m][nt][1] - mrow[m]);
                float p2 = EXP2F(sc[m][nt][2] - mrow[m]);
                float p3 = EXP2F(sc[m][nt][3] - mrow[m]);
                psum += (p0 + p1) + (p2 + p3);
                pw[nt * 2]     = pk2h(p0, p1);
                pw[nt * 2 + 1] = pk2h(p2, p3);
            }
            lsum[m] += psum;
            int prow = (wave * 32 + m * 16 + lrow) * LV;
            #pragma unroll
            for (int nt = 0; nt < 4; ++nt) {
                uint2 wv; wv.x = pw[nt * 2]; wv.y = pw[nt * 2 + 1];
                *(uint2*)(&Ps[prow + nt * 16 + quad * 4]) = wv;
            }
        }

        // PV (Ps same-wave write->read; DS ops wave-ordered)
        for (int c = 0; c < 2; ++c) {
            f16x8 pa0 = *(const f16x8*)(&Ps[(wave * 32 + lrow) * LV + c * 32 + quad * 8]);
            f16x8 pa1 = *(const f16x8*)(&Ps[(wave * 32 + 16 + lrow) * LV + c * 32 + quad * 8]);
            for (int dt = 0; dt < 8; ++dt) {
                f16x8 vb = *(const f16x8*)(&Vts[c * 4096 + (dt * 16 + lrow) * 32 + quad * 8]);
                Ofr[0][dt] = __builtin_amdgcn_mfma_f32_16x16x32_f16(pa0, vb, Ofr[0][dt], 0, 0, 0);
                Ofr[1][dt] = __builtin_amdgcn_mfma_f32_16x16x32_f16(pa1, vb, Ofr[1][dt], 0, 0, 0);
            }
        }
        __syncthreads();
    }

    // epilogue: O rows in C-layout (quad*4+r); ML stats per (m,lrow) at quad 0
    size_t obase = (size_t)(kz * NHEAD + h) * S_LEN;
    for (int m = 0; m < 2; ++m) {
        float rs = lsum[m];
        rs += __shfl_xor(rs, 16);
        rs += __shfl_xor(rs, 32);
        if (quad == 0) {
            int qrow = q0 + wave * 32 + m * 16 + lrow;
            ML[(obase + qrow) * 2]     = mrow[m];
            ML[(obase + qrow) * 2 + 1] = rs;
        }
        for (int r = 0; r < 4; ++r) {
            int qrow = q0 + wave * 32 + m * 16 + quad * 4 + r;
            unsigned short* op = OP + (obase + qrow) * HD;
            for (int dt = 0; dt < 8; ++dt)
                op[dt * 16 + lrow] = f2h(Ofr[m][dt][r]);
        }
    }
}

// ---------------- merge the two key-halves (log2 domain) -> fp16 Obf -------
__global__ __launch_bounds__(256) void flash_merge(const unsigned short* __restrict__ OP,
                                                   const float* __restrict__ ML,
                                                   unsigned short* __restrict__ Obf) {
    int row = blockIdx.x * 2 + (threadIdx.x >> 7);   // h*2048 + q
    int d   = threadIdx.x & 127;
    int h = row >> 11, q = row & 2047;
    size_t i0 = (size_t)h * S_LEN + q;
    size_t i1 = (size_t)(NHEAD + h) * S_LEN + q;
    float m0 = ML[i0 * 2], l0 = ML[i0 * 2 + 1];
    float m1 = ML[i1 * 2], l1 = ML[i1 * 2 + 1];
    float mf = fmaxf(m0, m1);
    float w0 = EXP2F(m0 - mf), w1 = EXP2F(m1 - mf);
    float inv = 1.f / (l0 * w0 + l1 * w1);
    float o = (h2f(OP[i0 * HD + d]) * w0 + h2f(OP[i1 * HD + d]) * w1) * inv;
    Obf[(size_t)q * HID + h * HD + d] = f2h(o);
}

// ---------------- launch ----------------
extern "C" void kernel_launch(void* const* d_in, const int* in_sizes, int n_in,
                              void* d_out, int out_size, void* d_ws, size_t ws_size,
                              hipStream_t stream) {
    const float* hs   = (const float*)d_in[0];
    const float* cosb = (const float*)d_in[1];
    const float* sinb = (const float*)d_in[2];
    const float* wq   = (const float*)d_in[3];
    const float* wk   = (const float*)d_in[4];
    const float* wv   = (const float*)d_in[5];
    const float* wo   = (const float*)d_in[6];
    float* out = (float*)d_out;
    char*  ws  = (char*)d_ws;

    // ws layout (phase-lifetime aliasing, ~101 MB):
    //  [0, 33.6M):     w_qk16 (dead after QK gemm) -> Q16 | K16 | kbias
    //  [33.6, 67.1M):  qk16 fp16 (dead after prep)  -> OP fp16 | ML
    //  [67.1M,...):    hs16 (->Obf) | w_v16 | w_o16 | Vt
    unsigned short* w_qk16 = (unsigned short*)(ws);
    unsigned short* Q16    = (unsigned short*)(ws);
    unsigned short* K16    = (unsigned short*)(ws + 8388608);
    float*          kbias  = (float*)(ws + 16777216);
    unsigned short* qk16   = (unsigned short*)(ws + 33554432);
    unsigned short* OP     = (unsigned short*)(ws + 33554432);    // aliases qk16
    float*          ML     = (float*)(ws + 50331648);
    unsigned short* hs16   = (unsigned short*)(ws + 67108864);
    unsigned short* Obf    = (unsigned short*)(ws + 67108864);    // aliases hs16
    unsigned short* w_v16  = (unsigned short*)(ws + 75497472);
    unsigned short* w_o16  = (unsigned short*)(ws + 83886080);
    unsigned short* Vt     = (unsigned short*)(ws + 92274688);

    static int use256 = -1;
    if (use256 < 0) {
        hipError_t e = hipFuncSetAttribute((const void*)gemm256_qk,
                                           hipFuncAttributeMaxDynamicSharedMemorySize,
                                           131072);
        use256 = (e == hipSuccess) ? 1 : 0;
    }

    // fused casts (5 segments, 28672 blocks)
    cast5<<<28672, 256, 0, stream>>>(hs, wq, wk, wv, wo, hs16, w_qk16, w_v16, w_o16);

    if (use256) {
        // QK projection [2048,8192]: 256^2 cross-phase pipelined GEMM (256 blocks = 1/CU)
        gemm256_qk<<<256, 512, 131072, stream>>>(hs16, w_qk16, qk16);
        // FUSED: V^T projection (256 blocks) + prep (8192 blocks) in ONE launch
        vt_prep<<<256 + 8192, 256, 0, stream>>>(w_v16, hs16, Vt, qk16,
                                                cosb, sinb, Q16, K16, kbias);
    } else {
        gemm_qkv<<<1280, 256, 0, stream>>>(hs16, w_qk16, w_v16, qk16, Vt);
        prep_qk<<<(NHEAD * S_LEN) / 4, 256, 0, stream>>>(qk16, cosb, sinb,
                                                         Q16, K16, kbias);
    }

    // flash attention (fp16 MFMA, key-split 2, XCD-remapped flat grid)
    flash_mfma<<<512, 256, 0, stream>>>(Q16, K16, Vt, kbias, OP, ML);
    // merge halves -> fp16 attn_out
    flash_merge<<<(NHEAD * S_LEN) / 2, 256, 0, stream>>>(OP, ML, Obf);
    // output projection: out = Obf @ w_o^T (fp32 out)
    gemm_nt_f16<false><<<dim3(16, 16), 256, 0, stream>>>(Obf, w_o16, out, S_LEN, HID, K_HID);
}